// Round 2
// baseline (2842.266 us; speedup 1.0000x reference)
//
#include <hip/hip_runtime.h>

#define NB 1024   // boxes
#define NC 151    // classes
#define NCP 152   // padded probs row stride (16B-aligned)
#define DF 4096   // feature dim
typedef unsigned long long u64;

// ---------------- GEMM: dists = fmap @ W + b (fp32 in, f64 accum) ----------------
// 4 rows per block; LDS interleaved sf[d*4 + r] so each d is one broadcast b128 read.
__global__ __launch_bounds__(192) void gemm_kernel(
    const float* __restrict__ fmap, const float* __restrict__ W,
    const float* __restrict__ bias, float* __restrict__ dists) {
  __shared__ float sf[4 * DF];  // 64 KiB
  int r0 = blockIdx.x * 4;
  const float4* src = (const float4*)(fmap + (size_t)r0 * DF);
  for (int i = threadIdx.x; i < 4 * (DF / 4); i += 192) {
    int r = i >> 10;       // row 0..3
    int q = i & 1023;      // float4 index within row
    float4 v = src[i];
    sf[(4 * q + 0) * 4 + r] = v.x;
    sf[(4 * q + 1) * 4 + r] = v.y;
    sf[(4 * q + 2) * 4 + r] = v.z;
    sf[(4 * q + 3) * 4 + r] = v.w;
  }
  __syncthreads();
  int c = threadIdx.x;
  if (c < NC) {
    double a0 = 0.0, a1 = 0.0, a2 = 0.0, a3 = 0.0;
    const float* w = W + c;
    const float4* sf4 = (const float4*)sf;
#pragma unroll 8
    for (int d = 0; d < DF; ++d) {
      float4 f = sf4[d];                       // broadcast across wave
      double wv = (double)w[(size_t)d * NC];   // coalesced across threads
      a0 += (double)f.x * wv;
      a1 += (double)f.y * wv;
      a2 += (double)f.z * wv;
      a3 += (double)f.w * wv;
    }
    float b = bias[c];
    dists[(size_t)(r0 + 0) * NC + c] = (float)a0 + b;
    dists[(size_t)(r0 + 1) * NC + c] = (float)a1 + b;
    dists[(size_t)(r0 + 2) * NC + c] = (float)a2 + b;
    dists[(size_t)(r0 + 3) * NC + c] = (float)a3 + b;
  }
}

// ---------------- softmax rows into padded probs, zero background col ----------------
__global__ __launch_bounds__(64) void softmax_kernel(
    const float* __restrict__ dists, float* __restrict__ probs) {
  int row = blockIdx.x;
  int t = threadIdx.x;
  const float* x = dists + (size_t)row * NC;
  float v0 = x[t];
  float v1 = x[t + 64];
  float v2 = (t + 128 < NC) ? x[t + 128] : -3.0e38f;
  float m = fmaxf(fmaxf(v0, v1), v2);
  for (int off = 32; off; off >>= 1) m = fmaxf(m, __shfl_down(m, off));
  m = __shfl(m, 0);
  float e0 = expf(v0 - m), e1 = expf(v1 - m);
  float e2 = (t + 128 < NC) ? expf(v2 - m) : 0.0f;
  float s = e0 + e1 + e2;
  for (int off = 32; off; off >>= 1) s += __shfl_down(s, off);
  s = __shfl(s, 0);
  float* p = probs + (size_t)row * NCP;
  p[t] = (t == 0) ? 0.0f : (e0 / s);
  p[t + 64] = e1 / s;
  if (t + 128 < NC) p[t + 128] = e2 / s;
  if (t == 0) p[NC] = -1.0f;  // pad col never wins a scan
}

// ---------------- transpose boxes to [C][N][4] ----------------
__global__ __launch_bounds__(256) void transpose_kernel(
    const float* __restrict__ boxes, float* __restrict__ boxes_t) {
  int idx = blockIdx.x * 256 + threadIdx.x;  // idx = c*NB + n
  if (idx >= NC * NB) return;
  int c = idx >> 10;
  int n = idx & (NB - 1);
  float4 b = *(const float4*)(boxes + ((size_t)n * NC + c) * 4);
  *(float4*)(boxes_t + (size_t)idx * 4) = b;
}

// ---------------- precompute overlap bitmask: mask[cl][b] = 1024 bits ----------------
__global__ __launch_bounds__(256) void mask_kernel(
    const float* __restrict__ boxes_t, u64* __restrict__ mask) {
#pragma clang fp contract(off)
  int cl = blockIdx.x >> 4;          // 151 classes
  int bb = (blockIdx.x & 15) * 64;   // 16 b-groups of 64
  __shared__ float4 sbox[NB];
  __shared__ float sarea[NB];
  const float4* col = (const float4*)(boxes_t + (size_t)cl * NB * 4);
  for (int i = threadIdx.x; i < NB; i += 256) {
    float4 b = col[i];
    sbox[i] = b;
    sarea[i] = (b.z - b.x + 1.0f) * (b.w - b.y + 1.0f);
  }
  __syncthreads();
  int wv = threadIdx.x >> 6, lane = threadIdx.x & 63;
  for (int j = 0; j < 16; ++j) {
    int b = bb + wv * 16 + j;
    float4 B = sbox[b];
    float areaB = sarea[b];
    u64 myword = 0;
#pragma unroll
    for (int k = 0; k < 16; ++k) {
      int r = k * 64 + lane;
      float4 R = sbox[r];
      float ix = fminf(B.z, R.z) - fmaxf(B.x, R.x) + 1.0f;
      float iy = fminf(B.w, R.w) - fmaxf(B.y, R.y) + 1.0f;
      ix = fmaxf(ix, 0.0f);
      iy = fmaxf(iy, 0.0f);
      float inter = ix * iy;
      float uni = sarea[r] + areaB - inter;
      float iou = inter / uni;            // IEEE div — must match numpy exactly
      u64 bal = __ballot(iou >= 0.5f);
      if (lane == k) myword = bal;
    }
    if (lane < 16) mask[((size_t)cl * NB + b) * 16 + lane] = myword;
  }
}

// ---------------- greedy commit: 1024 threads, one row per thread ----------------
__global__ __launch_bounds__(1024) void greedy_kernel(
    float* probs, const u64* __restrict__ mask, float* __restrict__ out_preds) {
  __shared__ u64 s_wkey[2][16];
  __shared__ int s_cl[2];

  int t = threadIdx.x;        // row
  int wv = t >> 6, lane = t & 63;

  // init: scan own row
  float rm;
  int ra;
  {
    const float4* p4 = (const float4*)(probs + (size_t)t * NCP);
    float m = 0.0f;
    int a = 0;
#pragma unroll 4
    for (int q = 0; q < NCP / 4; ++q) {
      float4 v = p4[q];
      int c0 = q * 4;
      if (v.x > m) { m = v.x; a = c0; }
      if (v.y > m) { m = v.y; a = c0 + 1; }
      if (v.z > m) { m = v.z; a = c0 + 2; }
      if (v.w > m) { m = v.w; a = c0 + 3; }
    }
    rm = m; ra = a;
  }
  bool committed = false;
  int commit = 0;

  for (int it = 0; it < NB; ++it) {
    int par = it & 1;
    // packed key: (value-key << 32) | (1023 - row); value-key 0 = committed w/o re-zero
    u64 vk = committed ? (rm < 0.0f ? 0ull : 1ull)
                       : ((u64)__float_as_uint(rm) + 1ull);
    u64 key = (vk << 32) | (u64)(NB - 1 - t);
    for (int off = 1; off < 64; off <<= 1) {
      u64 o = __shfl_xor(key, off);
      if (o > key) key = o;
    }
    if (lane == 0) s_wkey[par][wv] = key;
    __syncthreads();  // B1
    u64 bk = s_wkey[par][0];
#pragma unroll
    for (int w = 1; w < 16; ++w) {
      u64 o = s_wkey[par][w];
      if (o > bk) bk = o;
    }
    int b = NB - 1 - (int)(bk & 0xFFFFFFFFull);
    if (t == b) s_cl[par] = ra;
    __syncthreads();  // B2
    int cl = s_cl[par];

    u64 word = mask[((size_t)cl * NB + b) * 16 + wv];
    bool hit = (word >> lane) & 1;

    if (t == b) {
      commit = cl;
      committed = true;
      rm = -1.0f;  // row becomes all -1
    } else if (hit) {
      if (committed) {
        // committed row: entries are -1 except previously re-zeroed cols (0)
        if (rm < 0.0f) { rm = 0.0f; ra = cl; }
        else if (cl < ra) { ra = cl; }
      } else {
        float* pp = probs + (size_t)t * NCP;
        pp[cl] = 0.0f;
        if (ra == cl) {  // max may drop: rescan own row
          const float4* p4 = (const float4*)pp;
          float m = 0.0f;
          int a = 0;
#pragma unroll 4
          for (int q = 0; q < NCP / 4; ++q) {
            float4 v = p4[q];
            int c0 = q * 4;
            if (v.x > m) { m = v.x; a = c0; }
            if (v.y > m) { m = v.y; a = c0 + 1; }
            if (v.z > m) { m = v.z; a = c0 + 2; }
            if (v.w > m) { m = v.w; a = c0 + 3; }
          }
          rm = m; ra = a;
        }
      }
    }
    // no end barrier needed: next iter's shuffle uses registers only; LDS double-buffered
  }

  out_preds[t] = (float)commit;
}

// ---------------- host ----------------
extern "C" void kernel_launch(void* const* d_in, const int* in_sizes, int n_in,
                              void* d_out, int out_size, void* d_ws, size_t ws_size,
                              hipStream_t stream) {
  const float* obj_fmap = (const float*)d_in[0];  // [NB, DF]
  const float* W_out    = (const float*)d_in[1];  // [DF, NC]
  const float* b_out    = (const float*)d_in[2];  // [NC]
  const float* boxes    = (const float*)d_in[3];  // [NB, NC, 4]

  float* out_dists = (float*)d_out;            // NB*NC
  float* out_preds = (float*)d_out + NB * NC;  // NB (as float)

  float* probs   = (float*)d_ws;                        // NB*NCP floats (622,592 B)
  float* boxes_t = probs + (size_t)NB * NCP;            // NC*NB*4 floats (2,473,984 B)
  u64*   mask    = (u64*)(boxes_t + (size_t)NC * NB * 4);  // NC*NB*16 u64 (19.8 MB), 8B-aligned

  gemm_kernel<<<NB / 4, 192, 0, stream>>>(obj_fmap, W_out, b_out, out_dists);
  softmax_kernel<<<NB, 64, 0, stream>>>(out_dists, probs);
  transpose_kernel<<<(NC * NB + 255) / 256, 256, 0, stream>>>(boxes, boxes_t);
  mask_kernel<<<NC * 16, 256, 0, stream>>>(boxes_t, mask);
  greedy_kernel<<<1, 1024, 0, stream>>>(probs, mask, out_preds);
}

// Round 4
// 2179.661 us; speedup vs baseline: 1.3040x; 1.3040x over previous
//
#include <hip/hip_runtime.h>

#define NB 1024   // boxes
#define NC 151    // classes
#define NCP 152   // padded probs row stride (16B-aligned)
#define DF 4096   // feature dim
typedef unsigned long long u64;

// ---------------- GEMM: dists = fmap @ W + b (fp32 in, f64 accum) ----------------
__global__ __launch_bounds__(192) void gemm_kernel(
    const float* __restrict__ fmap, const float* __restrict__ W,
    const float* __restrict__ bias, float* __restrict__ dists) {
  __shared__ float sf[4 * DF];  // 64 KiB
  int r0 = blockIdx.x * 4;
  const float4* src = (const float4*)(fmap + (size_t)r0 * DF);
  for (int i = threadIdx.x; i < 4 * (DF / 4); i += 192) {
    int r = i >> 10;       // row 0..3
    int q = i & 1023;      // float4 index within row
    float4 v = src[i];
    sf[(4 * q + 0) * 4 + r] = v.x;
    sf[(4 * q + 1) * 4 + r] = v.y;
    sf[(4 * q + 2) * 4 + r] = v.z;
    sf[(4 * q + 3) * 4 + r] = v.w;
  }
  __syncthreads();
  int c = threadIdx.x;
  if (c < NC) {
    double a0 = 0.0, a1 = 0.0, a2 = 0.0, a3 = 0.0;
    const float* w = W + c;
    const float4* sf4 = (const float4*)sf;
#pragma unroll 8
    for (int d = 0; d < DF; ++d) {
      float4 f = sf4[d];                       // broadcast across wave
      double wv = (double)w[(size_t)d * NC];   // coalesced across threads
      a0 += (double)f.x * wv;
      a1 += (double)f.y * wv;
      a2 += (double)f.z * wv;
      a3 += (double)f.w * wv;
    }
    float b = bias[c];
    dists[(size_t)(r0 + 0) * NC + c] = (float)a0 + b;
    dists[(size_t)(r0 + 1) * NC + c] = (float)a1 + b;
    dists[(size_t)(r0 + 2) * NC + c] = (float)a2 + b;
    dists[(size_t)(r0 + 3) * NC + c] = (float)a3 + b;
  }
}

// ---------------- softmax rows into padded probs, zero background col ----------------
__global__ __launch_bounds__(64) void softmax_kernel(
    const float* __restrict__ dists, float* __restrict__ probs) {
  int row = blockIdx.x;
  int t = threadIdx.x;
  const float* x = dists + (size_t)row * NC;
  float v0 = x[t];
  float v1 = x[t + 64];
  float v2 = (t + 128 < NC) ? x[t + 128] : -3.0e38f;
  float m = fmaxf(fmaxf(v0, v1), v2);
  for (int off = 32; off; off >>= 1) m = fmaxf(m, __shfl_down(m, off));
  m = __shfl(m, 0);
  float e0 = expf(v0 - m), e1 = expf(v1 - m);
  float e2 = (t + 128 < NC) ? expf(v2 - m) : 0.0f;
  float s = e0 + e1 + e2;
  for (int off = 32; off; off >>= 1) s += __shfl_down(s, off);
  s = __shfl(s, 0);
  float* p = probs + (size_t)row * NCP;
  p[t] = (t == 0) ? 0.0f : (e0 / s);
  p[t + 64] = e1 / s;
  if (t + 128 < NC) p[t + 128] = e2 / s;
  if (t == 0) p[NC] = -1.0f;  // pad col never wins a scan
}

// ---------------- transpose boxes to [C][N][4] ----------------
__global__ __launch_bounds__(256) void transpose_kernel(
    const float* __restrict__ boxes, float* __restrict__ boxes_t) {
  int idx = blockIdx.x * 256 + threadIdx.x;  // idx = c*NB + n
  if (idx >= NC * NB) return;
  int c = idx >> 10;
  int n = idx & (NB - 1);
  float4 b = *(const float4*)(boxes + ((size_t)n * NC + c) * 4);
  *(float4*)(boxes_t + (size_t)idx * 4) = b;
}

// ---------------- precompute overlap bitmask: mask[cl][b] = 1024 bits ----------------
__global__ __launch_bounds__(256) void mask_kernel(
    const float* __restrict__ boxes_t, u64* __restrict__ mask) {
#pragma clang fp contract(off)
  int cl = blockIdx.x >> 4;          // 151 classes
  int bb = (blockIdx.x & 15) * 64;   // 16 b-groups of 64
  __shared__ float4 sbox[NB];
  __shared__ float sarea[NB];
  const float4* col = (const float4*)(boxes_t + (size_t)cl * NB * 4);
  for (int i = threadIdx.x; i < NB; i += 256) {
    float4 b = col[i];
    sbox[i] = b;
    sarea[i] = (b.z - b.x + 1.0f) * (b.w - b.y + 1.0f);
  }
  __syncthreads();
  int wv = threadIdx.x >> 6, lane = threadIdx.x & 63;
  for (int j = 0; j < 16; ++j) {
    int b = bb + wv * 16 + j;
    float4 B = sbox[b];
    float areaB = sarea[b];
    u64 myword = 0;
#pragma unroll
    for (int k = 0; k < 16; ++k) {
      int r = k * 64 + lane;
      float4 R = sbox[r];
      float ix = fminf(B.z, R.z) - fmaxf(B.x, R.x) + 1.0f;
      float iy = fminf(B.w, R.w) - fmaxf(B.y, R.y) + 1.0f;
      ix = fmaxf(ix, 0.0f);
      iy = fmaxf(iy, 0.0f);
      float inter = ix * iy;
      float uni = sarea[r] + areaB - inter;
      float iou = inter / uni;            // IEEE div — must match numpy exactly
      u64 bal = __ballot(iou >= 0.5f);
      if (lane == k) myword = bal;
    }
    if (lane < 16) mask[((size_t)cl * NB + b) * 16 + lane] = myword;
  }
}

// ---------------- greedy commit: ONE wave, 16 rows per lane, zero barriers ----------------
template <int CTRL, int ROWMASK>
__device__ __forceinline__ float dpp_max_step(float v) {
  int x = __float_as_int(v);
  int t = __builtin_amdgcn_update_dpp(x, x, CTRL, ROWMASK, 0xf, false);
  return fmaxf(v, __int_as_float(t));
}

__global__ __launch_bounds__(64) void greedy_kernel(
    float* probs, const u64* __restrict__ mask, float* __restrict__ out_preds) {
  int lane = threadIdx.x;
  float rm[16];
  int ra[16];
  int cm[16];
  unsigned committed = 0;

  // ---- init: scan my 16 rows ----
#pragma unroll
  for (int r = 0; r < 16; ++r) {
    const float4* p4 = (const float4*)(probs + (size_t)((lane << 4) | r) * NCP);
    float m = 0.0f;
    int a = 0;
    for (int q = 0; q < NCP / 4; ++q) {
      float4 v = p4[q];
      int c0 = q * 4;
      if (v.x > m) { m = v.x; a = c0; }
      if (v.y > m) { m = v.y; a = c0 + 1; }
      if (v.z > m) { m = v.z; a = c0 + 2; }
      if (v.w > m) { m = v.w; a = c0 + 3; }
    }
    rm[r] = m; ra[r] = a; cm[r] = 0;
  }

  for (int it = 0; it < NB; ++it) {
    // ---- local argmax over my 16 rows (ascending, strict > => smallest row on tie) ----
    float bv = rm[0];
    int bloc = 0, bcl = ra[0];
#pragma unroll
    for (int r = 1; r < 16; ++r)
      if (rm[r] > bv) { bv = rm[r]; bloc = r; bcl = ra[r]; }

    // ---- wave max via DPP (lane 63 ends with global max) ----
    float wv = bv;
    wv = dpp_max_step<0x111, 0xf>(wv);  // row_shr:1
    wv = dpp_max_step<0x112, 0xf>(wv);  // row_shr:2
    wv = dpp_max_step<0x114, 0xf>(wv);  // row_shr:4
    wv = dpp_max_step<0x118, 0xf>(wv);  // row_shr:8
    wv = dpp_max_step<0x142, 0xa>(wv);  // row_bcast:15 -> rows 1,3
    wv = dpp_max_step<0x143, 0xc>(wv);  // row_bcast:31 -> row 2,3
    float wmax = __int_as_float(__builtin_amdgcn_readlane(__float_as_int(wv), 63));

    // ---- winner lane = smallest lane matching max (= smallest row) ----
    u64 ball = __ballot(bv == wmax);
    int winner = __ffsll(ball) - 1;
    int packed = (bloc << 8) | bcl;
    int pw = __builtin_amdgcn_readlane(packed, winner);
    int b = (winner << 4) | (pw >> 8);
    int cl = pw & 0xff;

    // ---- one coalesced 128B mask-column load; my 16 bits ----
    u64 word = mask[((size_t)cl * NB + b) * 16 + (lane >> 2)];
    unsigned hits = (unsigned)(word >> ((lane & 3) << 4)) & 0xFFFFu;

    // ---- update my rows ----
#pragma unroll
    for (int r = 0; r < 16; ++r) {
      int grow = (lane << 4) | r;
      if (grow == b) {
        committed |= (1u << r);
        rm[r] = -1.0f;       // row becomes all -1
        cm[r] = cl;          // commit (or re-commit)
      } else if ((hits >> r) & 1) {
        if (committed & (1u << r)) {
          // committed row: -1 everywhere except re-zeroed cols (0)
          if (rm[r] < 0.0f) { rm[r] = 0.0f; ra[r] = cl; }
          else if (cl < ra[r]) ra[r] = cl;
        } else {
          float* pp = probs + (size_t)grow * NCP;
          pp[cl] = 0.0f;
          if (ra[r] == cl) {  // max may drop: rescan own row (treat col cl as 0)
            const float4* p4 = (const float4*)pp;
            float m = 0.0f;
            int a = 0;
            for (int q = 0; q < NCP / 4; ++q) {
              float4 v = p4[q];
              int c0 = q * 4;
              if (c0 != cl && v.x > m) { m = v.x; a = c0; }
              if (c0 + 1 != cl && v.y > m) { m = v.y; a = c0 + 1; }
              if (c0 + 2 != cl && v.z > m) { m = v.z; a = c0 + 2; }
              if (c0 + 3 != cl && v.w > m) { m = v.w; a = c0 + 3; }
            }
            rm[r] = m; ra[r] = a;
          }
        }
      }
    }
  }

  // ---- write commits (each lane owns its rows; single final store) ----
#pragma unroll
  for (int r = 0; r < 16; ++r)
    out_preds[(lane << 4) | r] = (float)cm[r];
}

// ---------------- host ----------------
extern "C" void kernel_launch(void* const* d_in, const int* in_sizes, int n_in,
                              void* d_out, int out_size, void* d_ws, size_t ws_size,
                              hipStream_t stream) {
  const float* obj_fmap = (const float*)d_in[0];  // [NB, DF]
  const float* W_out    = (const float*)d_in[1];  // [DF, NC]
  const float* b_out    = (const float*)d_in[2];  // [NC]
  const float* boxes    = (const float*)d_in[3];  // [NB, NC, 4]

  float* out_dists = (float*)d_out;            // NB*NC
  float* out_preds = (float*)d_out + NB * NC;  // NB (as float)

  float* probs   = (float*)d_ws;                        // NB*NCP floats
  float* boxes_t = probs + (size_t)NB * NCP;            // NC*NB*4 floats
  u64*   mask    = (u64*)(boxes_t + (size_t)NC * NB * 4);  // NC*NB*16 u64 (19.8 MB)

  gemm_kernel<<<NB / 4, 192, 0, stream>>>(obj_fmap, W_out, b_out, out_dists);
  softmax_kernel<<<NB, 64, 0, stream>>>(out_dists, probs);
  transpose_kernel<<<(NC * NB + 255) / 256, 256, 0, stream>>>(boxes, boxes_t);
  mask_kernel<<<NC * 16, 256, 0, stream>>>(boxes_t, mask);
  greedy_kernel<<<1, 64, 0, stream>>>(probs, mask, out_preds);
}